// Round 3
// baseline (103.183 us; speedup 1.0000x reference)
//
#include <hip/hip_runtime.h>
#include <hip/hip_bf16.h>

#define Tt 512
#define Bb 512
#define DV 256
#define DQ 128
#define DH 64
#define CTXN (Tt * DV)  // 131072 floats: context part of d_out

typedef __attribute__((ext_vector_type(8))) short bf16x8;
typedef __attribute__((ext_vector_type(4))) float f32x4;

__device__ __forceinline__ unsigned short f2bf(float x) {
  unsigned u = __float_as_uint(x);
  u += 0x7FFFu + ((u >> 16) & 1u);   // RNE
  return (unsigned short)(u >> 16);
}

// ---- Kernel 0a: qh[b,h] = sum_q W2[h,q]*query[b,q] + b2[h] + b1[h] ----
__global__ void qh_kernel(const float* __restrict__ query,
                          const float* __restrict__ W2,
                          const float* __restrict__ b1,
                          const float* __restrict__ b2,
                          float* __restrict__ qh) {
  int b = blockIdx.x;      // 512
  int h = threadIdx.x;     // 64
  __shared__ float q[DQ];
  q[h]      = query[b * DQ + h];
  q[h + 64] = query[b * DQ + h + 64];
  __syncthreads();
  const float* w2r = W2 + h * DQ;
  float acc = 0.f;
#pragma unroll 8
  for (int k = 0; k < DQ; ++k) acc = fmaf(w2r[k], q[k], acc);
  qh[b * DH + h] = acc + b1[h] + b2[h];
}

// ---- Kernel 0b: W1 f32 -> bf16 ----
__global__ void w1_cvt_kernel(const float* __restrict__ W1,
                              unsigned short* __restrict__ w1bf) {
  int i = blockIdx.x * 256 + threadIdx.x;  // grid 64 -> 16384
  w1bf[i] = f2bf(W1[i]);
}

// ---- Kernel 1: scores. Block = 64 rows of [B*T, 256] @ W1^T -> tanh -> Wv dot ----
// A (values rows) loaded DIRECTLY global->reg->bf16 (each row used by exactly one
// wave: no reuse, so no LDS staging). Only B (W1, reused by all 4 waves) is in LDS.
// sT[t*512 + b] = score
__global__ __launch_bounds__(256, 4) void score_kernel(
    const float* __restrict__ values,
    const unsigned short* __restrict__ w1bf,
    const float* __restrict__ qh,
    const float* __restrict__ Wv,
    const float* __restrict__ bv,
    float* __restrict__ sT) {
  __shared__ __align__(16) unsigned short lB[DH * DV];  // 32 KB, swizzled bf16
  const int tid = threadIdx.x;
  const int m0 = blockIdx.x * 64;
  const int bidx = m0 >> 9;  // all 64 rows share the same b (64 | 512)

  // stage W1 bf16 -> lB (16B units), XOR-swizzle byte ^= (row&7)<<4
  const uint4* w1v = (const uint4*)w1bf;
#pragma unroll
  for (int i = 0; i < 8; ++i) {
    int vec = i * 256 + tid;        // 2048 units of 16B
    uint4 d = w1v[vec];
    int row = vec >> 5;             // 32 units per 256-elem row
    int u = vec & 31;
    int byte = (row << 9) + (u << 4);
    *(uint4*)((char*)lB + (byte ^ ((row & 7) << 4))) = d;
  }
  __syncthreads();

  const int wv = tid >> 6;        // wave 0..3 -> A rows 16*wv .. +15
  const int lane = tid & 63;
  const int lrow = lane & 15;
  const int g = lane >> 4;        // k-group

  f32x4 acc[4];
#pragma unroll
  for (int nt = 0; nt < 4; ++nt) acc[nt] = (f32x4){0.f, 0.f, 0.f, 0.f};

  const int arow = wv * 16 + lrow;
  const float* ap = values + (size_t)(m0 + arow) * DV;

#pragma unroll
  for (int ks = 0; ks < 8; ++ks) {
    // lane's A fragment: row arow, elements ks*32 + g*8 .. +7 (f32 -> bf16)
    const float* fp = ap + ks * 32 + g * 8;
    float4 f0 = *(const float4*)(fp);
    float4 f1 = *(const float4*)(fp + 4);
    bf16x8 af;
    af[0] = (short)f2bf(f0.x); af[1] = (short)f2bf(f0.y);
    af[2] = (short)f2bf(f0.z); af[3] = (short)f2bf(f0.w);
    af[4] = (short)f2bf(f1.x); af[5] = (short)f2bf(f1.y);
    af[6] = (short)f2bf(f1.z); af[7] = (short)f2bf(f1.w);
    int k2 = (ks * 32 + g * 8) * 2;  // byte offset of k within a B row
#pragma unroll
    for (int nt = 0; nt < 4; ++nt) {
      int brow = nt * 16 + lrow;
      bf16x8 bf = *(const bf16x8*)((const char*)lB +
                                   (((brow << 9) + k2) ^ ((brow & 7) << 4)));
      acc[nt] = __builtin_amdgcn_mfma_f32_16x16x32_bf16(af, bf, acc[nt], 0, 0, 0);
    }
  }

  // epilogue: h + qh -> tanh -> * Wv, reduce over 64 cols
  float bv0 = bv[0];
  float sc[4] = {0.f, 0.f, 0.f, 0.f};
#pragma unroll
  for (int nt = 0; nt < 4; ++nt) {
    int col = nt * 16 + lrow;
    float qv = qh[bidx * DH + col];
    float wvc = Wv[col];
#pragma unroll
    for (int j = 0; j < 4; ++j) {
      float hv = acc[nt][j] + qv;
      float e = __expf(2.f * hv);
      float th = (e - 1.f) / (e + 1.f);
      sc[j] = fmaf(th, wvc, sc[j]);
    }
  }
#pragma unroll
  for (int j = 0; j < 4; ++j) {
    float v = sc[j];
    v += __shfl_xor(v, 1);
    v += __shfl_xor(v, 2);
    v += __shfl_xor(v, 4);
    v += __shfl_xor(v, 8);
    sc[j] = v;
  }
  if (lrow == 0) {
#pragma unroll
    for (int j = 0; j < 4; ++j) {
      int m = m0 + wv * 16 + g * 4 + j;
      int tt = m & (Tt - 1);
      sT[tt * Bb + bidx] = sc[j] + bv0;
    }
  }
}

// ---- Kernel 2: per-t softmax over b + weighted context reduction ----
// 1024 threads (16 waves) per t: 32 waves/CU at 2 blocks/CU for latency hiding.
__global__ __launch_bounds__(1024, 8) void ctx_kernel(
    const float* __restrict__ values,
    const float* __restrict__ sT,
    float* __restrict__ out) {
  const int t = blockIdx.x;
  const int tid = threadIdx.x;
  const int wv = tid >> 6, lane = tid & 63;
  __shared__ float wbuf[Bb];
  __shared__ float smax[16], ssum[16];
  __shared__ float4 cred[16][64];

  float s = -1e30f;
  if (tid < Bb) s = sT[t * Bb + tid];
  float mx = s;
#pragma unroll
  for (int d = 1; d < 64; d <<= 1) mx = fmaxf(mx, __shfl_xor(mx, d));
  if (lane == 0) smax[wv] = mx;
  __syncthreads();
  mx = smax[0];
#pragma unroll
  for (int i = 1; i < 16; ++i) mx = fmaxf(mx, smax[i]);
  float w = (tid < Bb) ? __expf(s - mx) : 0.f;
  float zs = w;
#pragma unroll
  for (int d = 1; d < 64; d <<= 1) zs += __shfl_xor(zs, d);
  if (lane == 0) ssum[wv] = zs;
  __syncthreads();
  float Z = 0.f;
#pragma unroll
  for (int i = 0; i < 16; ++i) Z += ssum[i];
  float wn = w / Z;
  if (tid < Bb) {
    wbuf[tid] = wn;
    out[CTXN + tid * Tt + t] = wn;   // attention_weights[b,t]
  }
  __syncthreads();

  // context[t,:] = sum_b w[b] * values[b,t,:]; wave wv owns b = wv + 16*i
  const float4* vp = (const float4*)values;
  size_t base = ((size_t)wv * Tt + t) * (DV / 4) + lane;
  const size_t stride = (size_t)16 * Tt * (DV / 4);
  float4 acc = make_float4(0.f, 0.f, 0.f, 0.f);
#pragma unroll 4
  for (int i = 0; i < 32; ++i) {
    float4 v = vp[base];
    base += stride;
    float wb = wbuf[wv + (i << 4)];
    acc.x = fmaf(wb, v.x, acc.x);
    acc.y = fmaf(wb, v.y, acc.y);
    acc.z = fmaf(wb, v.z, acc.z);
    acc.w = fmaf(wb, v.w, acc.w);
  }
  cred[wv][lane] = acc;
  __syncthreads();
  if (wv == 0) {
    float4 tot = cred[0][lane];
#pragma unroll
    for (int i = 1; i < 16; ++i) {
      float4 a = cred[i][lane];
      tot.x += a.x; tot.y += a.y; tot.z += a.z; tot.w += a.w;
    }
    ((float4*)out)[t * (DV / 4) + lane] = tot;
  }
}

extern "C" void kernel_launch(void* const* d_in, const int* in_sizes, int n_in,
                              void* d_out, int out_size, void* d_ws, size_t ws_size,
                              hipStream_t stream) {
  const float* query  = (const float*)d_in[0];
  const float* values = (const float*)d_in[1];
  const float* W1     = (const float*)d_in[2];
  const float* b1     = (const float*)d_in[3];
  const float* W2     = (const float*)d_in[4];
  const float* b2     = (const float*)d_in[5];
  const float* Wv     = (const float*)d_in[6];
  const float* bv     = (const float*)d_in[7];
  float* out = (float*)d_out;
  char* ws = (char*)d_ws;
  float* qh            = (float*)ws;                      // 512*64*4   = 128 KB
  unsigned short* w1bf = (unsigned short*)(ws + 131072);  // 16384*2    =  32 KB
  float* sT            = (float*)(ws + 131072 + 32768);   // 512*512*4  =   1 MB

  hipLaunchKernelGGL(qh_kernel, dim3(Bb), dim3(DH), 0, stream, query, W2, b1, b2, qh);
  hipLaunchKernelGGL(w1_cvt_kernel, dim3(64), dim3(256), 0, stream, W1, w1bf);
  hipLaunchKernelGGL(score_kernel, dim3((Bb * Tt) / 64), dim3(256), 0, stream,
                     values, w1bf, qh, Wv, bv, sT);
  hipLaunchKernelGGL(ctx_kernel, dim3(Tt), dim3(1024), 0, stream, values, sT, out);
}